// Round 2
// baseline (1049.454 us; speedup 1.0000x reference)
//
#include <hip/hip_runtime.h>
#include <hip/hip_bf16.h>
#include <math.h>

// FCTP with all-scalar right operand:
//   o[n,w,m] = alpha * sum_{u,v} x[n,u,m] * z[n,v] * w[u,v,w]
// Fused as: t[n,u,w] = sum_v z[n,v]*wb[u][w][v]  (MFMA, K=96 padded from 89)
//           o[n,w,m] += t[n,u,w] * x[n,u,m]      (VALU fold, x from LDS)
// rows(M)=nodes from A=z frags (held in regs, loaded once per WG),
// cols(N)=w from B=wb frags (global loads, L2-resident, no LDS, no barrier in u-loop).

typedef __attribute__((ext_vector_type(8))) short short8;
typedef __attribute__((ext_vector_type(4))) float float4v;

static constexpr int N_FEAT = 480;

__device__ __forceinline__ unsigned short f2bf(float v) {
    __hip_bfloat16 h = __float2bfloat16(v);
    return __builtin_bit_cast(unsigned short, h);
}

// Repack w[u][v(89)][wcol] fp32 -> wb[u][wcol][v(96 pad)] bf16 (v contiguous for B-frag b128 loads)
template<int U>
__global__ void pack_w_kernel(const float* __restrict__ w, unsigned short* __restrict__ wb) {
    const int total = U * U * 96;
    int i = blockIdx.x * 256 + threadIdx.x;
    if (i >= total) return;
    int v = i % 96;
    int uw = i / 96;
    int wcol = uw % U;
    int u = uw / U;
    float val = (v < 89) ? w[(u * 89 + v) * U + wcol] : 0.0f;
    wb[i] = f2bf(val);
}

// U = mul (= out mul), D = 2l+1, WSUB = 16-wide w-subtiles per wave, OFF = col offset in x/out
template<int U, int D, int WSUB, int OFF>
__global__ __launch_bounds__(256, 2)
void fctp_kernel(const float* __restrict__ x, const float* __restrict__ z,
                 const unsigned short* __restrict__ wb, float* __restrict__ out,
                 int nN, float alpha) {
    constexpr int C = U * D;                 // x columns for this l
    __shared__ unsigned short xlds[C][132];  // [u*D+m][n_local], stride 132 (8B-aligned rows, bank step 2)

    const int tid  = threadIdx.x;
    const int lane = tid & 63;
    const int wave = tid >> 6;
    const int q    = lane >> 4;   // quad 0..3
    const int c    = lane & 15;   // col-in-tile / row-in-A
    const int wn   = wave >> 1;   // wave's node half (0..1)
    const int ww   = wave & 1;    // wave's w half   (0..1)

    const int nbase = blockIdx.x * 128;
    const int wbase = blockIdx.y * (2 * WSUB * 16) + ww * (WSUB * 16);
    const int nwave = nbase + wn * 64;

    // ---- stage x tile to LDS as bf16, layout [c][n_local] ----
    for (int e = tid; e < 128 * C; e += 256) {
        int nl = e / C;
        int cc = e - nl * C;
        int ng = nbase + nl;
        float v = (ng < nN) ? x[ng * N_FEAT + OFF + cc] : 0.0f;
        xlds[cc][nl] = f2bf(v);
    }

    // ---- A fragments (z rows, bf16), once per WG; A[m=lane&15][k=q*8+j] ----
    short8 afrag[4][3];
#pragma unroll
    for (int nt = 0; nt < 4; ++nt) {
        int ng = nwave + nt * 16 + c;
        if (ng >= nN) ng = nN - 1;           // clamp; padded rows fold with x=0 and stores are guarded
        const float* zrow = z + ng * 89;
#pragma unroll
        for (int kk = 0; kk < 3; ++kk) {
            short8 f;
#pragma unroll
            for (int j = 0; j < 8; ++j) {
                int v = kk * 32 + q * 8 + j;
                float val = (v < 89) ? zrow[v] : 0.0f;
                f[j] = (short)f2bf(val);
            }
            afrag[nt][kk] = f;
        }
    }
    __syncthreads();

    // ---- accumulators ----
    float4v oacc[4][WSUB][D];
#pragma unroll
    for (int nt = 0; nt < 4; ++nt)
#pragma unroll
        for (int wt = 0; wt < WSUB; ++wt)
#pragma unroll
            for (int m = 0; m < D; ++m)
                oacc[nt][wt][m] = float4v{0.f, 0.f, 0.f, 0.f};

    // per-wt B base pointers: B[n=lane&15 -> w col][k=q*8+j -> v]
    const unsigned short* wptr[WSUB];
#pragma unroll
    for (int wt = 0; wt < WSUB; ++wt)
        wptr[wt] = wb + (wbase + wt * 16 + c) * 96 + q * 8;

    short8 bfr[2][WSUB][3];
#pragma unroll
    for (int wt = 0; wt < WSUB; ++wt)
#pragma unroll
        for (int kk = 0; kk < 3; ++kk)
            bfr[0][wt][kk] = *reinterpret_cast<const short8*>(wptr[wt] + kk * 32);

#pragma unroll 2
    for (int u = 0; u < U; ++u) {
        const int cur = u & 1, nxt = cur ^ 1;
        const int un = (u + 1 < U) ? (u + 1) : u;   // prefetch next-u B frags
#pragma unroll
        for (int wt = 0; wt < WSUB; ++wt)
#pragma unroll
            for (int kk = 0; kk < 3; ++kk)
                bfr[nxt][wt][kk] = *reinterpret_cast<const short8*>(wptr[wt] + un * (U * 96) + kk * 32);

        // t tiles: 16 nodes x 16 w, K=96
        float4v t[4][WSUB];
#pragma unroll
        for (int nt = 0; nt < 4; ++nt)
#pragma unroll
            for (int wt = 0; wt < WSUB; ++wt) {
                float4v acc = {0.f, 0.f, 0.f, 0.f};
                acc = __builtin_amdgcn_mfma_f32_16x16x32_bf16(afrag[nt][0], bfr[cur][wt][0], acc, 0, 0, 0);
                acc = __builtin_amdgcn_mfma_f32_16x16x32_bf16(afrag[nt][1], bfr[cur][wt][1], acc, 0, 0, 0);
                acc = __builtin_amdgcn_mfma_f32_16x16x32_bf16(afrag[nt][2], bfr[cur][wt][2], acc, 0, 0, 0);
                t[nt][wt] = acc;
            }

        // fold: o[n,w,m] += t[n,w] * x[n,u,m]; rows of reg r are n = q*4+r (broadcast over 16 cols)
        // node-local-in-WG = wn*64 + nt*16 + q*4 + r   (wn*64 was the R1 bug)
#pragma unroll
        for (int nt = 0; nt < 4; ++nt) {
#pragma unroll
            for (int m = 0; m < D; ++m) {
                const unsigned short* p = &xlds[u * D + m][wn * 64 + nt * 16 + q * 4];
                uint2 xv = *reinterpret_cast<const uint2*>(p);
                float xf[4];
                xf[0] = __uint_as_float(xv.x << 16);
                xf[1] = __uint_as_float(xv.x & 0xffff0000u);
                xf[2] = __uint_as_float(xv.y << 16);
                xf[3] = __uint_as_float(xv.y & 0xffff0000u);
#pragma unroll
                for (int wt = 0; wt < WSUB; ++wt)
#pragma unroll
                    for (int r = 0; r < 4; ++r)
                        oacc[nt][wt][m][r] += t[nt][wt][r] * xf[r];
            }
        }
    }

    // ---- epilogue: C layout row = q*4+r, col = lane&15 ----
#pragma unroll
    for (int nt = 0; nt < 4; ++nt)
#pragma unroll
        for (int wt = 0; wt < WSUB; ++wt) {
            const int wg = wbase + wt * 16 + c;
#pragma unroll
            for (int r = 0; r < 4; ++r) {
                const int ng = nwave + nt * 16 + q * 4 + r;
                if (ng < nN) {
#pragma unroll
                    for (int m = 0; m < D; ++m)
                        out[ng * N_FEAT + OFF + wg * D + m] = alpha * oacc[nt][wt][m][r];
                }
            }
        }
}

extern "C" void kernel_launch(void* const* d_in, const int* in_sizes, int n_in,
                              void* d_out, int out_size, void* d_ws, size_t ws_size,
                              hipStream_t stream) {
    const float* x  = (const float*)d_in[0];
    const float* z  = (const float*)d_in[1];
    const float* w0 = (const float*)d_in[2];
    const float* w1 = (const float*)d_in[3];
    const float* w2 = (const float*)d_in[4];
    float* out = (float*)d_out;
    const int N = in_sizes[0] / N_FEAT;

    unsigned short* wb0 = (unsigned short*)d_ws;            // 128*128*96 bf16
    unsigned short* wb1 = wb0 + 128 * 128 * 96;             // 64*64*96
    unsigned short* wb2 = wb1 + 64 * 64 * 96;               // 32*32*96  (total ~4.1 MB of ws)

    pack_w_kernel<128><<<(128 * 128 * 96 + 255) / 256, 256, 0, stream>>>(w0, wb0);
    pack_w_kernel<64><<<(64 * 64 * 96 + 255) / 256, 256, 0, stream>>>(w1, wb1);
    pack_w_kernel<32><<<(32 * 32 * 96 + 255) / 256, 256, 0, stream>>>(w2, wb2);

    const int nblocks = (N + 127) / 128;
    const float a0 = 1.0f / sqrtf(128.0f * 89.0f);
    const float a1 = 1.0f / sqrtf(64.0f * 89.0f);
    const float a2 = 1.0f / sqrtf(32.0f * 89.0f);

    // l0: 128x0e  — WG 128n x 64w, 2 w-blocks
    fctp_kernel<128, 1, 2, 0><<<dim3(nblocks, 2), 256, 0, stream>>>(x, z, wb0, out, N, a0);
    // l1: 64x1e   — WG 128n x 32w, 2 w-blocks
    fctp_kernel<64, 3, 1, 128><<<dim3(nblocks, 2), 256, 0, stream>>>(x, z, wb1, out, N, a1);
    // l2: 32x2e   — WG 128n x 32w, 1 w-block
    fctp_kernel<32, 5, 1, 320><<<dim3(nblocks, 1), 256, 0, stream>>>(x, z, wb2, out, N, a2);
}

// Round 3
// 947.292 us; speedup vs baseline: 1.1078x; 1.1078x over previous
//
#include <hip/hip_runtime.h>
#include <hip/hip_bf16.h>
#include <math.h>

// FCTP with all-scalar right operand:
//   o[n,w,m] = alpha * sum_{u,v} x[n,u,m] * z[n,v] * w[u,v,w]
// Fused: t[w,n] = sum_v wb[u][w][v]*z[n,v]   (MFMA, A=w-frag rows=w, B=z-frag cols=node)
//        o[n,w,m] += t[w,n] * x[n,u,m]       (per-lane scalar x: fp32 LDS read, no unpack)
// C/D layout: row(w) = q*4+r, col(node) = lane&15  -> epilogue is contiguous 4D-float chunks.

typedef __attribute__((ext_vector_type(8))) short short8;
typedef __attribute__((ext_vector_type(4))) float float4v;

static constexpr int N_FEAT = 480;

__device__ __forceinline__ unsigned short f2bf(float v) {
    __hip_bfloat16 h = __float2bfloat16(v);
    return __builtin_bit_cast(unsigned short, h);
}

// Repack w[u][v(89)][wcol] fp32 -> wb[u][wcol][v(96 pad)] bf16 (v contiguous, 16B-aligned rows)
template<int U>
__global__ void pack_w_kernel(const float* __restrict__ w, unsigned short* __restrict__ wb) {
    const int total = U * U * 96;
    int i = blockIdx.x * 256 + threadIdx.x;
    if (i >= total) return;
    int v = i % 96;
    int uw = i / 96;
    int wcol = uw % U;
    int u = uw / U;
    float val = (v < 89) ? w[(u * 89 + v) * U + wcol] : 0.0f;
    wb[i] = f2bf(val);
}

// WG = 64 nodes x (GW*WT*16) w-cols. 4 waves: wn = wave%GN (node group), ww = wave/GN (w group).
// NT node tiles of 16 per wave, WT w tiles of 16 per wave.
template<int U, int D, int NT, int WT, int OFF>
__global__ __launch_bounds__(256, 3)
void fctp_kernel(const float* __restrict__ x, const float* __restrict__ z,
                 const unsigned short* __restrict__ wb, float* __restrict__ out,
                 int nN, float alpha) {
    constexpr int C  = U * D;
    constexpr int SP = C + 4;              // fp32 LDS row stride (dwords): %4==0 (b128 stage), %32==4 (2-way max on fold reads)
    constexpr int GN = 64 / (NT * 16);
    __shared__ float xlds[64 * SP];

    const int tid  = threadIdx.x;
    const int lane = tid & 63;
    const int wave = tid >> 6;
    const int q    = lane >> 4;   // quad: k-offset in frags, w-subrow in C
    const int c    = lane & 15;   // w row in A-frag, node col in B-frag/C
    const int wn   = wave % GN;
    const int ww   = wave / GN;
    const int nbase = blockIdx.x * 64;

    // ---- stage x tile to LDS as fp32 [n_local][col] ----
    constexpr int CQ = C / 4;
#pragma unroll
    for (int it = 0; it < C / 16; ++it) {
        int e  = it * 256 + tid;
        int nl = e / CQ;
        int cq = e - nl * CQ;
        int ng = nbase + nl;
        float4v v = {0.f, 0.f, 0.f, 0.f};
        if (ng < nN)
            v = *reinterpret_cast<const float4v*>(x + ng * N_FEAT + OFF + cq * 4);
        *reinterpret_cast<float4v*>(&xlds[nl * SP + cq * 4]) = v;
    }

    // ---- z frags (B operand): lane c -> node, k = q*8+j ----
    short8 zfr[NT][3];
#pragma unroll
    for (int nt = 0; nt < NT; ++nt) {
        int ng = nbase + wn * (NT * 16) + nt * 16 + c;
        if (ng >= nN) ng = nN - 1;         // clamp; stores guarded, fold x=0 for pad rows
        const float* zrow = z + ng * 89;
#pragma unroll
        for (int kk = 0; kk < 3; ++kk) {
            short8 f;
#pragma unroll
            for (int j = 0; j < 8; ++j) {
                int v = kk * 32 + q * 8 + j;
                float val = (v < 89) ? zrow[v] : 0.0f;
                f[j] = (short)f2bf(val);
            }
            zfr[nt][kk] = f;
        }
    }
    __syncthreads();

    // ---- accumulators ----
    float4v oacc[NT][WT][D];
#pragma unroll
    for (int nt = 0; nt < NT; ++nt)
#pragma unroll
        for (int wt = 0; wt < WT; ++wt)
#pragma unroll
            for (int m = 0; m < D; ++m)
                oacc[nt][wt][m] = float4v{0.f, 0.f, 0.f, 0.f};

    // ---- A(w) frag pointers: lane c -> w row, k = q*8+j ----
    const unsigned short* wptr[WT];
#pragma unroll
    for (int wt = 0; wt < WT; ++wt)
        wptr[wt] = wb + (ww * (WT * 16) + wt * 16 + c) * 96 + q * 8;

    short8 bfr[2][WT][3];
#pragma unroll
    for (int wt = 0; wt < WT; ++wt)
#pragma unroll
        for (int kk = 0; kk < 3; ++kk)
            bfr[0][wt][kk] = *reinterpret_cast<const short8*>(wptr[wt] + kk * 32);

#pragma unroll 2
    for (int u = 0; u < U; ++u) {
        const int cur = u & 1, nxt = cur ^ 1;
        const int un = (u + 1 < U) ? (u + 1) : u;
#pragma unroll
        for (int wt = 0; wt < WT; ++wt)
#pragma unroll
            for (int kk = 0; kk < 3; ++kk)
                bfr[nxt][wt][kk] = *reinterpret_cast<const short8*>(wptr[wt] + un * (U * 96) + kk * 32);

        // per-lane x scalars for this u (independent of MFMA results -> schedules early)
        float xv[NT][D];
#pragma unroll
        for (int nt = 0; nt < NT; ++nt)
#pragma unroll
            for (int m = 0; m < D; ++m)
                xv[nt][m] = xlds[(wn * (NT * 16) + nt * 16 + c) * SP + u * D + m];

        // t tiles (16w x 16n, K=96) + immediate fold
#pragma unroll
        for (int nt = 0; nt < NT; ++nt)
#pragma unroll
            for (int wt = 0; wt < WT; ++wt) {
                float4v acc = {0.f, 0.f, 0.f, 0.f};
                acc = __builtin_amdgcn_mfma_f32_16x16x32_bf16(bfr[cur][wt][0], zfr[nt][0], acc, 0, 0, 0);
                acc = __builtin_amdgcn_mfma_f32_16x16x32_bf16(bfr[cur][wt][1], zfr[nt][1], acc, 0, 0, 0);
                acc = __builtin_amdgcn_mfma_f32_16x16x32_bf16(bfr[cur][wt][2], zfr[nt][2], acc, 0, 0, 0);
#pragma unroll
                for (int m = 0; m < D; ++m)
#pragma unroll
                    for (int r = 0; r < 4; ++r)
                        oacc[nt][wt][m][r] += acc[r] * xv[nt][m];
            }
    }

    // ---- epilogue: lane writes 4D contiguous floats per (nt,wt) ----
#pragma unroll
    for (int nt = 0; nt < NT; ++nt) {
        const int node = nbase + wn * (NT * 16) + nt * 16 + c;
        if (node >= nN) continue;
#pragma unroll
        for (int wt = 0; wt < WT; ++wt) {
            const int w0 = ww * (WT * 16) + wt * 16 + q * 4;   // multiple of 4 -> 16B-aligned stores
            float vals[4 * D];
#pragma unroll
            for (int r = 0; r < 4; ++r)
#pragma unroll
                for (int m = 0; m < D; ++m)
                    vals[r * D + m] = alpha * oacc[nt][wt][m][r];
            float* o = out + node * N_FEAT + OFF + w0 * D;
#pragma unroll
            for (int j = 0; j < D; ++j)
                *reinterpret_cast<float4v*>(o + j * 4) =
                    float4v{vals[j * 4 + 0], vals[j * 4 + 1], vals[j * 4 + 2], vals[j * 4 + 3]};
        }
    }
}

extern "C" void kernel_launch(void* const* d_in, const int* in_sizes, int n_in,
                              void* d_out, int out_size, void* d_ws, size_t ws_size,
                              hipStream_t stream) {
    const float* x  = (const float*)d_in[0];
    const float* z  = (const float*)d_in[1];
    const float* w0 = (const float*)d_in[2];
    const float* w1 = (const float*)d_in[3];
    const float* w2 = (const float*)d_in[4];
    float* out = (float*)d_out;
    const int N = in_sizes[0] / N_FEAT;

    unsigned short* wb0 = (unsigned short*)d_ws;            // 128*128*96 bf16
    unsigned short* wb1 = wb0 + 128 * 128 * 96;             // 64*64*96
    unsigned short* wb2 = wb1 + 64 * 64 * 96;               // 32*32*96

    pack_w_kernel<128><<<(128 * 128 * 96 + 255) / 256, 256, 0, stream>>>(w0, wb0);
    pack_w_kernel<64><<<(64 * 64 * 96 + 255) / 256, 256, 0, stream>>>(w1, wb1);
    pack_w_kernel<32><<<(32 * 32 * 96 + 255) / 256, 256, 0, stream>>>(w2, wb2);

    const int nblocks = (N + 63) / 64;
    const float a0 = 1.0f / sqrtf(128.0f * 89.0f);
    const float a1 = 1.0f / sqrtf(64.0f * 89.0f);
    const float a2 = 1.0f / sqrtf(32.0f * 89.0f);

    // l0: 128x0e — WG 64n x 128w; waves 64n x 32w (NT=4, WT=2)
    fctp_kernel<128, 1, 4, 2, 0><<<nblocks, 256, 0, stream>>>(x, z, wb0, out, N, a0);
    // l1: 64x1e  — WG 64n x 64w; waves 32n x 32w (NT=2, WT=2)
    fctp_kernel<64, 3, 2, 2, 128><<<nblocks, 256, 0, stream>>>(x, z, wb1, out, N, a1);
    // l2: 32x2e  — WG 64n x 32w; waves 16n x 32w (NT=1, WT=2)
    fctp_kernel<32, 5, 1, 2, 320><<<nblocks, 256, 0, stream>>>(x, z, wb2, out, N, a2);
}